// Round 6
// baseline (351.133 us; speedup 1.0000x reference)
//
#include <hip/hip_runtime.h>

typedef __attribute__((ext_vector_type(8))) short bf16x8;
typedef __attribute__((ext_vector_type(4))) float f32x4;

#define B_N 8192
#define D_N 256
#define K_N 64

__device__ __forceinline__ unsigned short bf16_rne(float f) {
  unsigned u = __builtin_bit_cast(unsigned, f);
  u += 0x7fffu + ((u >> 16) & 1u);
  return (unsigned short)(u >> 16);
}
__device__ __forceinline__ float bf16_f32(unsigned short h) {
  return __builtin_bit_cast(float, (unsigned)h << 16);
}

// DMA 16B/lane global->LDS. LDS dest: wave-uniform base + lane*16 (linear).
__device__ __forceinline__ void gload_lds16(const void* g, void* l) {
  __builtin_amdgcn_global_load_lds(
      (const __attribute__((address_space(1))) unsigned int*)g,
      (__attribute__((address_space(3))) unsigned int*)l, 16, 0, 0);
}

// One-time f32 -> bf16 (hi) + bf16 (residual lo) split.
__global__ void convert_kernel(const float* __restrict__ src,
                               ushort* __restrict__ hi, ushort* __restrict__ lo,
                               int n4) {
  int idx = blockIdx.x * blockDim.x + threadIdx.x;
  int stride = gridDim.x * blockDim.x;
  for (int i = idx; i < n4; i += stride) {
    float4 v = ((const float4*)src)[i];
    ushort4 h, l;
    h.x = bf16_rne(v.x); l.x = bf16_rne(v.x - bf16_f32(h.x));
    h.y = bf16_rne(v.y); l.y = bf16_rne(v.y - bf16_f32(h.y));
    h.z = bf16_rne(v.z); l.z = bf16_rne(v.z - bf16_f32(h.z));
    h.w = bf16_rne(v.w); l.w = bf16_rne(v.w - bf16_f32(h.w));
    ((ushort4*)hi)[i] = h;
    ((ushort4*)lo)[i] = l;
  }
}

// Sigma-RESIDENT xsx kernel. part[b][k][eh] = sum_{d, e in eh-half}
// Sigma_k[d][e] x[b][e] x[b][d], 3-term bf16 split, f32 accum.
//
// Block = (k, eh, bg): stages Sigma_k[256 d][128 e-half] hi+lo (128 KB) into
// LDS ONCE (swizzled source, linear gload_lds dest), one barrier, then loops
// 8 b-tiles x K=128 with ZERO barriers in the load/MFMA stream: A-fragments
// (Xh/Xl) load directly global->VGPR (X is L2/L3-hot; R5 validated this
// path), B from read-only LDS. Waves run independently; compiler pipelines
// the whole K-loop. Per b-tile: cross-wave d-reduce via 2 compute-gated
// barriers, e-half partial written to part (summed in loss_kernel).
__global__ __launch_bounds__(512, 2) void xsx_res_kernel(
    const float* __restrict__ X,
    const ushort* __restrict__ Xh, const ushort* __restrict__ Xl,
    const ushort* __restrict__ Sh, const ushort* __restrict__ Sl,
    float* __restrict__ part) {
  __shared__ __align__(16) ushort Bh[D_N][128];  // 64 KB  Sigma hi [d][e-swz]
  __shared__ __align__(16) ushort Bl[D_N][128];  // 64 KB  Sigma lo
  __shared__ float red[4][128];                  //  2 KB

  const int tid = threadIdx.x;
  const int lane = tid & 63;
  const int wid = tid >> 6;  // 0..7
  const int wm = wid >> 2;   // 0..1 : b-half (64 rows) of the 128-row b-tile
  const int wn = wid & 3;    // 0..3 : d quarter (64 cols)
  const int lr = lane & 15;
  const int lk = lane >> 4;

  // Block mapping: 1024 blocks = 8 xcd * (16 (k,eh) groups * 8 b-groups).
  // Each XCD owns k in [xcd*8, xcd*8+8) -> its Sigma set (2 MB) L2-resident.
  const int bid = blockIdx.x;
  const int xcd = bid & 7;
  const int idx = bid >> 3;             // 0..127
  const int keh = xcd * 16 + (idx & 15);
  const int kk = keh >> 1;              // 0..63
  const int eh = keh & 1;               // e-half
  const int bg = idx >> 4;              // 0..7 -> 1024 b-rows each
  const int bbase = bg * 1024;

  // ---- stage Sigma tile once: rows d=0..255, cols = eh*128..+128 ----
  // Swizzle (both-sides, rule 21): LDS phys 16B-chunk p holds logical chunk
  // p ^ (d & 15). gload_lds dest is linear; the permutation is applied on
  // the per-lane global SOURCE address here, and on the ds_read side below.
  {
    const size_t sg = (size_t)kk * (D_N * D_N) + eh * 128;
    for (int i = 0; i < 8; ++i) {
      const int r0 = (i * 8 + wid) * 4;      // 4 rows (256B each) per issue
      const int row = r0 + (lane >> 4);
      const int cl = (lane & 15) ^ (row & 15);
      const size_t src = sg + (size_t)row * D_N + cl * 8;
      gload_lds16(Sh + src, &Bh[r0][0]);
      gload_lds16(Sl + src, &Bl[r0][0]);
    }
  }
  __syncthreads();  // the only load-gating barrier in the kernel

  for (int bt = 0; bt < 8; ++bt) {
    const int brow0 = bbase + bt * 128 + wm * 64;  // wave's first b-row

    f32x4 acc[4][4];
#pragma unroll
    for (int mi = 0; mi < 4; ++mi)
#pragma unroll
      for (int ni = 0; ni < 4; ++ni) acc[mi][ni] = (f32x4){0.f, 0.f, 0.f, 0.f};

#pragma unroll
    for (int kh = 0; kh < 4; ++kh) {  // e-chunks of 32 within the 128-half
      // A-frags direct from global: row = brow0 + mi*16 + lr,
      // e = eh*128 + kh*32 + lk*8 (A layout: lane holds A[lr][lk*8+j]).
      const size_t ae =
          (size_t)(brow0 + lr) * D_N + eh * 128 + kh * 32 + lk * 8;
      bf16x8 ah[4], al[4], bh[4], blo[4];
#pragma unroll
      for (int mi = 0; mi < 4; ++mi)
        ah[mi] = *(const bf16x8*)(Xh + ae + mi * 16 * D_N);
#pragma unroll
      for (int mi = 0; mi < 4; ++mi)
        al[mi] = *(const bf16x8*)(Xl + ae + mi * 16 * D_N);
      // B-frags from LDS: d-row = wn*64 + ni*16 + lr (row&15 == lr),
      // logical chunk kh*4+lk -> phys chunk (kh*4+lk) ^ lr.
      const int bc = ((kh * 4 + lk) ^ lr) * 8;
#pragma unroll
      for (int ni = 0; ni < 4; ++ni)
        bh[ni] = *(const bf16x8*)&Bh[wn * 64 + ni * 16 + lr][bc];
#pragma unroll
      for (int ni = 0; ni < 4; ++ni)
        blo[ni] = *(const bf16x8*)&Bl[wn * 64 + ni * 16 + lr][bc];

      __builtin_amdgcn_s_setprio(1);
#pragma unroll
      for (int ni = 0; ni < 4; ++ni)
#pragma unroll
        for (int mi = 0; mi < 4; ++mi)
          acc[mi][ni] = __builtin_amdgcn_mfma_f32_16x16x32_bf16(
              ah[mi], bh[ni], acc[mi][ni], 0, 0, 0);
#pragma unroll
      for (int ni = 0; ni < 4; ++ni)
#pragma unroll
        for (int mi = 0; mi < 4; ++mi)
          acc[mi][ni] = __builtin_amdgcn_mfma_f32_16x16x32_bf16(
              al[mi], bh[ni], acc[mi][ni], 0, 0, 0);
#pragma unroll
      for (int ni = 0; ni < 4; ++ni)
#pragma unroll
        for (int mi = 0; mi < 4; ++mi)
          acc[mi][ni] = __builtin_amdgcn_mfma_f32_16x16x32_bf16(
              ah[mi], blo[ni], acc[mi][ni], 0, 0, 0);
      __builtin_amdgcn_s_setprio(0);
    }

    // Epilogue for this b-tile: p[b] = sum_d Yp[b][d] * X[b][d] over the
    // wave's 64 d-cols. C/D layout (verified): col=lane&15, row=(lane>>4)*4+j.
    float p[4][4];
#pragma unroll
    for (int mi = 0; mi < 4; ++mi)
#pragma unroll
      for (int jj = 0; jj < 4; ++jj) p[mi][jj] = 0.f;
#pragma unroll
    for (int mi = 0; mi < 4; ++mi) {
#pragma unroll
      for (int jj = 0; jj < 4; ++jj) {
        const int brow = brow0 + mi * 16 + lk * 4 + jj;
        const float* xr = X + (size_t)brow * D_N + wn * 64 + lr;
#pragma unroll
        for (int ni = 0; ni < 4; ++ni)
          p[mi][jj] = fmaf(acc[mi][ni][jj], xr[ni * 16], p[mi][jj]);
      }
    }
#pragma unroll
    for (int mi = 0; mi < 4; ++mi)
#pragma unroll
      for (int jj = 0; jj < 4; ++jj) {
        float v = p[mi][jj];
        v += __shfl_xor(v, 1);
        v += __shfl_xor(v, 2);
        v += __shfl_xor(v, 4);
        v += __shfl_xor(v, 8);
        p[mi][jj] = v;
      }
    __syncthreads();  // previous b-tile's red reads done (compute-gated)
    if (lr == 0) {
#pragma unroll
      for (int mi = 0; mi < 4; ++mi)
#pragma unroll
        for (int jj = 0; jj < 4; ++jj)
          red[wn][wm * 64 + mi * 16 + lk * 4 + jj] = p[mi][jj];
    }
    __syncthreads();
    if (tid < 128) {
      const float s = red[0][tid] + red[1][tid] + red[2][tid] + red[3][tid];
      part[((size_t)(bbase + bt * 128 + tid) * K_N + kk) * 2 + eh] = s;
    }
  }
}

// Fallback (small ws): in-block convert, 128-tile (round-1 verified path).
// Writes xsx with nparts=1 layout.
__global__ __launch_bounds__(512, 2) void xsx_fallback(
    const float* __restrict__ X, const float* __restrict__ Sigma,
    float* __restrict__ xsx) {
  constexpr int BM = 128, KT = 32;
  __shared__ __align__(16) ushort Ah[BM][KT];
  __shared__ __align__(16) ushort Al[BM][KT];
  __shared__ __align__(16) ushort Bh[D_N][KT];
  __shared__ __align__(16) ushort Bl[D_N][KT];
  __shared__ float red[4][BM];

  const int tid = threadIdx.x;
  const int lane = tid & 63;
  const int wid = tid >> 6;
  const int wm = wid >> 2;
  const int wn = wid & 3;
  const int lr = lane & 15;
  const int lk = lane >> 4;

  const int b0 = blockIdx.x * BM;
  const int kk = blockIdx.y;
  const size_t soff = (size_t)kk * D_N * D_N;

  f32x4 acc[4][4];
#pragma unroll
  for (int mi = 0; mi < 4; ++mi)
#pragma unroll
    for (int ni = 0; ni < 4; ++ni) acc[mi][ni] = (f32x4){0.f, 0.f, 0.f, 0.f};

  for (int ec = 0; ec < D_N / KT; ++ec) {
    const int e0 = ec * KT;
    __syncthreads();
#pragma unroll
    for (int r = 0; r < 2; ++r) {
      const int i = tid + 512 * r;
      const int row = i >> 3, c4 = (i & 7) * 4;
      const float4 v = *(const float4*)(X + (size_t)(b0 + row) * D_N + e0 + c4);
      ushort4 h, l;
      h.x = bf16_rne(v.x); l.x = bf16_rne(v.x - bf16_f32(h.x));
      h.y = bf16_rne(v.y); l.y = bf16_rne(v.y - bf16_f32(h.y));
      h.z = bf16_rne(v.z); l.z = bf16_rne(v.z - bf16_f32(h.z));
      h.w = bf16_rne(v.w); l.w = bf16_rne(v.w - bf16_f32(h.w));
      *(ushort4*)&Ah[row][c4] = h;
      *(ushort4*)&Al[row][c4] = l;
    }
#pragma unroll
    for (int r = 0; r < 4; ++r) {
      const int i = tid + 512 * r;
      const int d = i >> 3, c4 = (i & 7) * 4;
      const float4 v = *(const float4*)(Sigma + soff + (size_t)d * D_N + e0 + c4);
      ushort4 h, l;
      h.x = bf16_rne(v.x); l.x = bf16_rne(v.x - bf16_f32(h.x));
      h.y = bf16_rne(v.y); l.y = bf16_rne(v.y - bf16_f32(h.y));
      h.z = bf16_rne(v.z); l.z = bf16_rne(v.z - bf16_f32(h.z));
      h.w = bf16_rne(v.w); l.w = bf16_rne(v.w - bf16_f32(h.w));
      *(ushort4*)&Bh[d][c4] = h;
      *(ushort4*)&Bl[d][c4] = l;
    }
    __syncthreads();

    bf16x8 ah[4], al[4];
#pragma unroll
    for (int mi = 0; mi < 4; ++mi) {
      ah[mi] = *(const bf16x8*)&Ah[wm * 64 + mi * 16 + lr][lk * 8];
      al[mi] = *(const bf16x8*)&Al[wm * 64 + mi * 16 + lr][lk * 8];
    }
#pragma unroll
    for (int ni = 0; ni < 4; ++ni) {
      const bf16x8 bh = *(const bf16x8*)&Bh[wn * 64 + ni * 16 + lr][lk * 8];
      const bf16x8 bl = *(const bf16x8*)&Bl[wn * 64 + ni * 16 + lr][lk * 8];
#pragma unroll
      for (int mi = 0; mi < 4; ++mi) {
        acc[mi][ni] = __builtin_amdgcn_mfma_f32_16x16x32_bf16(ah[mi], bh, acc[mi][ni], 0, 0, 0);
        acc[mi][ni] = __builtin_amdgcn_mfma_f32_16x16x32_bf16(al[mi], bh, acc[mi][ni], 0, 0, 0);
        acc[mi][ni] = __builtin_amdgcn_mfma_f32_16x16x32_bf16(ah[mi], bl, acc[mi][ni], 0, 0, 0);
      }
    }
  }

  float p[4][4];
#pragma unroll
  for (int mi = 0; mi < 4; ++mi)
#pragma unroll
    for (int jj = 0; jj < 4; ++jj) p[mi][jj] = 0.f;
#pragma unroll
  for (int mi = 0; mi < 4; ++mi) {
#pragma unroll
    for (int jj = 0; jj < 4; ++jj) {
      const int brow = b0 + wm * 64 + mi * 16 + lk * 4 + jj;
      const float* xr = X + (size_t)brow * D_N + wn * 64 + lr;
#pragma unroll
      for (int ni = 0; ni < 4; ++ni)
        p[mi][jj] = fmaf(acc[mi][ni][jj], xr[ni * 16], p[mi][jj]);
    }
  }
#pragma unroll
  for (int mi = 0; mi < 4; ++mi)
#pragma unroll
    for (int jj = 0; jj < 4; ++jj) {
      float v = p[mi][jj];
      v += __shfl_xor(v, 1);
      v += __shfl_xor(v, 2);
      v += __shfl_xor(v, 4);
      v += __shfl_xor(v, 8);
      p[mi][jj] = v;
    }
  if (lr == 0) {
#pragma unroll
    for (int mi = 0; mi < 4; ++mi)
#pragma unroll
      for (int jj = 0; jj < 4; ++jj)
        red[wn][wm * 64 + mi * 16 + lk * 4 + jj] = p[mi][jj];
  }
  __syncthreads();
  if (tid < BM) {
    const float s = red[0][tid] + red[1][tid] + red[2][tid] + red[3][tid];
    xsx[(size_t)(b0 + tid) * K_N + kk] = s;
  }
}

// One wave per batch row b; lane k owns class k in [0,64).
// nparts: xsx entries per (b,k) to sum (2 for e-half partials, 1 fallback).
__global__ __launch_bounds__(256) void loss_kernel(
    const float* __restrict__ X, const int* __restrict__ y,
    const float* __restrict__ mu, const int* __restrict__ loss_type,
    const float* __restrict__ xsx, float* __restrict__ out, int nparts) {
  __shared__ float mu_s[D_N * K_N];  // 64 KB
  __shared__ float x_s[4][D_N];      //  4 KB
  const int tid = threadIdx.x;
  const int wid = tid >> 6;
  const int lane = tid & 63;
  const int b = blockIdx.x * 4 + wid;

  for (int i = tid; i < D_N * K_N / 4; i += 256)
    ((float4*)mu_s)[i] = ((const float4*)mu)[i];
  ((float4*)&x_s[wid][0])[lane] = ((const float4*)(X + (size_t)b * D_N))[lane];
  __syncthreads();

  const int yb = y[b];
  const int lt = loss_type[0];

  float logit = 0.f;
#pragma unroll 8
  for (int d = 0; d < D_N; ++d)
    logit = fmaf(x_s[wid][d], mu_s[d * K_N + lane], logit);

  float term;
  if (lt == 1) {
    float xv;
    if (nparts == 2) {
      const float2 pv =
          *(const float2*)(xsx + ((size_t)b * K_N + lane) * 2);
      xv = pv.x + pv.y;
    } else {
      xv = xsx[(size_t)b * K_N + lane];
    }
    const float psi = sqrtf(fmaxf(xv + logit * logit, 0.f));
    const float bk = (lane <= yb) ? 1.f : 0.f;
    const float kap = ((lane == yb) ? 1.f : 0.f) - 0.5f * bk;
    // psi/2 - softplus(psi) = -psi/2 - log1p(exp(-psi)) for psi >= 0
    term = logit * kap + bk * (-0.5f * psi - log1pf(expf(-psi)));
  } else {
    const float sp = (logit > 0.f) ? (logit + log1pf(expf(-logit)))
                                   : log1pf(expf(logit));
    term = ((lane == yb) ? logit : 0.f) - ((lane <= yb) ? sp : 0.f);
  }
#pragma unroll
  for (int s = 1; s < 64; s <<= 1) term += __shfl_xor(term, s);
  if (lane == 0) out[b] = -term;
}

extern "C" void kernel_launch(void* const* d_in, const int* in_sizes, int n_in,
                              void* d_out, int out_size, void* d_ws, size_t ws_size,
                              hipStream_t stream) {
  const float* X = (const float*)d_in[0];
  const int* y = (const int*)d_in[1];
  const float* mu = (const float*)d_in[2];
  const float* Sigma = (const float*)d_in[3];
  const int* lt = (const int*)d_in[4];
  float* out = (float*)d_out;

  const size_t XN = (size_t)B_N * D_N;        // 2,097,152 elems
  const size_t SN = (size_t)K_N * D_N * D_N;  // 4,194,304 elems
  const size_t xh_off = 0;
  const size_t xl_off = xh_off + XN * 2;
  const size_t sh_off = xl_off + XN * 2;
  const size_t sl_off = sh_off + SN * 2;
  const size_t part_off = sl_off + SN * 2;
  const size_t need = part_off + (size_t)B_N * K_N * 2 * 4;  // ~29.4 MB

  char* w = (char*)d_ws;
  if (ws_size >= need) {
    ushort* Xh = (ushort*)(w + xh_off);
    ushort* Xl = (ushort*)(w + xl_off);
    ushort* Sh = (ushort*)(w + sh_off);
    ushort* Sl = (ushort*)(w + sl_off);
    float* part = (float*)(w + part_off);
    hipLaunchKernelGGL(convert_kernel, dim3(1024), dim3(256), 0, stream,
                       X, Xh, Xl, (int)(XN / 4));
    hipLaunchKernelGGL(convert_kernel, dim3(2048), dim3(256), 0, stream,
                       Sigma, Sh, Sl, (int)(SN / 4));
    hipLaunchKernelGGL(xsx_res_kernel, dim3(1024), dim3(512), 0, stream,
                       X, Xh, Xl, Sh, Sl, part);
    hipLaunchKernelGGL(loss_kernel, dim3(B_N / 4), dim3(256), 0, stream,
                       X, y, mu, lt, part, out, 2);
  } else {
    float* xsx = (float*)w;  // needs 2 MB
    hipLaunchKernelGGL(xsx_fallback, dim3(B_N / 128, K_N), dim3(512), 0, stream,
                       X, Sigma, xsx);
    hipLaunchKernelGGL(loss_kernel, dim3(B_N / 4), dim3(256), 0, stream,
                       X, y, mu, lt, xsx, out, 1);
  }
}

// Round 7
// 233.504 us; speedup vs baseline: 1.5038x; 1.5038x over previous
//
#include <hip/hip_runtime.h>

typedef __attribute__((ext_vector_type(8))) short bf16x8;
typedef __attribute__((ext_vector_type(4))) float f32x4;

#define B_N 8192
#define D_N 256
#define K_N 64

__device__ __forceinline__ unsigned short bf16_rne(float f) {
  unsigned u = __builtin_bit_cast(unsigned, f);
  u += 0x7fffu + ((u >> 16) & 1u);
  return (unsigned short)(u >> 16);
}
__device__ __forceinline__ float bf16_f32(unsigned short h) {
  return __builtin_bit_cast(float, (unsigned)h << 16);
}

// DMA 16B/lane global->LDS. LDS dest: wave-uniform base + lane*16 (linear).
__device__ __forceinline__ void gload_lds16(const void* g, void* l) {
  __builtin_amdgcn_global_load_lds(
      (const __attribute__((address_space(1))) unsigned int*)g,
      (__attribute__((address_space(3))) unsigned int*)l, 16, 0, 0);
}

// One-time f32 -> bf16 (hi) + bf16 (residual lo) split.
__global__ void convert_kernel(const float* __restrict__ src,
                               ushort* __restrict__ hi, ushort* __restrict__ lo,
                               int n4) {
  int idx = blockIdx.x * blockDim.x + threadIdx.x;
  int stride = gridDim.x * blockDim.x;
  for (int i = idx; i < n4; i += stride) {
    float4 v = ((const float4*)src)[i];
    ushort4 h, l;
    h.x = bf16_rne(v.x); l.x = bf16_rne(v.x - bf16_f32(h.x));
    h.y = bf16_rne(v.y); l.y = bf16_rne(v.y - bf16_f32(h.y));
    h.z = bf16_rne(v.z); l.z = bf16_rne(v.z - bf16_f32(h.z));
    h.w = bf16_rne(v.w); l.w = bf16_rne(v.w - bf16_f32(h.w));
    ((ushort4*)hi)[i] = h;
    ((ushort4*)lo)[i] = l;
  }
}

// xsx[b][k] = x_b^T Sigma_k x_b.  OCCUPANCY-FIRST design:
// BM=64 b-rows, 4 waves (256 thr, 1 wave/SIMD per block), wave w owns d-cols
// [w*64, w*64+64). LDS = EXACTLY 40 KB (A 8KB + B 32KB; reduce buffer
// aliases dead A space) -> 4 blocks/CU co-resident, 16 waves/CU: block i's
// stage-drain hides under blocks j,k,l's MFMA (m114 implicit overlap).
// R1's proven simple 2-barrier single-buffer loop; NO setprio/sched_barrier/
// counted-vmcnt (all measured neutral-to-harmful in rounds 3-6).
// Staging: gload_lds16, pre-swizzled global source, phys_chunk = c ^
// ((row>>1)&3) both-sides -> 2-way max bank aliasing (free per m136).
// XCD k-major mapping: each XCD owns 8 k (Sigma 2 MB, L2-resident); 8
// neighbor blocks share one X panel. 3-term bf16 split [XhSh|XlSh|XhSl],
// f32 accum; epilogue dots with exact f32 X.
__global__ __launch_bounds__(256, 3) void xsx64_kernel(
    const float* __restrict__ X,
    const ushort* __restrict__ Xh, const ushort* __restrict__ Xl,
    const ushort* __restrict__ Sh, const ushort* __restrict__ Sl,
    float* __restrict__ xsx) {
  __shared__ __align__(16) ushort smem[20480];  // 40960 B exactly
  ushort(*Ah)[32] = (ushort(*)[32])(smem);          // [64][32]
  ushort(*Al)[32] = (ushort(*)[32])(smem + 2048);   // [64][32]
  ushort(*Bh)[32] = (ushort(*)[32])(smem + 4096);   // [256][32]
  ushort(*Bl)[32] = (ushort(*)[32])(smem + 12288);  // [256][32]
  float(*red)[64] = (float(*)[64])(smem);           // aliases Ah (dead then)

  const int tid = threadIdx.x;
  const int lane = tid & 63;
  const int wid = tid >> 6;  // 0..3 : d quarter
  const int lr = lane & 15;
  const int lk = lane >> 4;

  // XCD k-major mapping: 8192 blocks = 8 xcd * (8 k * 128 b-groups).
  const int bid = blockIdx.x;
  const int xcd = bid & 7;
  const int j = bid >> 3;          // 0..1023
  const int kk = xcd * 8 + (j & 7);
  const int b0 = (j >> 3) * 64;    // b-group
  const size_t soff = (size_t)kk * D_N * D_N;

  // Staging source swizzle (both-sides, rule 21): lane l writes LDS phys
  // chunk (l&3) of row base+(l>>2); it must read logical chunk
  // (l&3) ^ ((l>>3)&3)  [ == phys ^ ((row>>1)&3) ].
  const int srow = lane >> 2;                           // 0..15
  const int sc = ((lane & 3) ^ ((lane >> 3) & 3)) * 8;  // swizzled ushort col
  // ds_read side: phys chunk = lk ^ ((lr>>1)&3) (row-terms vanish mod 4).
  const int rdc = (lk ^ ((lr >> 1) & 3)) * 8;

  f32x4 acc[4][4];
#pragma unroll
  for (int mi = 0; mi < 4; ++mi)
#pragma unroll
    for (int ni = 0; ni < 4; ++ni) acc[mi][ni] = (f32x4){0.f, 0.f, 0.f, 0.f};

  const size_t arow = (size_t)(b0 + wid * 16 + srow) * D_N + sc;

  for (int ec = 0; ec < 8; ++ec) {
    const int e0 = ec * 32;
    __syncthreads();  // prior compute done before overwrite
    // A: 64 rows; wave w stages rows w*16..+16 (1 issue hi, 1 lo).
    gload_lds16(Xh + arow + e0, &Ah[wid * 16][0]);
    gload_lds16(Xl + arow + e0, &Al[wid * 16][0]);
    // B: 256 rows; wave w stages rows w*64 + i*16 (4 issues hi, 4 lo).
#pragma unroll
    for (int i = 0; i < 4; ++i) {
      const size_t brow =
          soff + (size_t)(wid * 64 + i * 16 + srow) * D_N + sc + e0;
      gload_lds16(Sh + brow, &Bh[wid * 64 + i * 16][0]);
      gload_lds16(Sl + brow, &Bl[wid * 64 + i * 16][0]);
    }
    __syncthreads();  // compiler drains vmcnt(0) before barrier

    bf16x8 ah[4], al[4];
#pragma unroll
    for (int mi = 0; mi < 4; ++mi) {
      ah[mi] = *(const bf16x8*)&Ah[mi * 16 + lr][rdc];
      al[mi] = *(const bf16x8*)&Al[mi * 16 + lr][rdc];
    }
#pragma unroll
    for (int ni = 0; ni < 4; ++ni) {
      const bf16x8 bh = *(const bf16x8*)&Bh[wid * 64 + ni * 16 + lr][rdc];
      const bf16x8 bl = *(const bf16x8*)&Bl[wid * 64 + ni * 16 + lr][rdc];
#pragma unroll
      for (int mi = 0; mi < 4; ++mi)
        acc[mi][ni] = __builtin_amdgcn_mfma_f32_16x16x32_bf16(
            ah[mi], bh, acc[mi][ni], 0, 0, 0);
#pragma unroll
      for (int mi = 0; mi < 4; ++mi)
        acc[mi][ni] = __builtin_amdgcn_mfma_f32_16x16x32_bf16(
            al[mi], bh, acc[mi][ni], 0, 0, 0);
#pragma unroll
      for (int mi = 0; mi < 4; ++mi)
        acc[mi][ni] = __builtin_amdgcn_mfma_f32_16x16x32_bf16(
            ah[mi], bl, acc[mi][ni], 0, 0, 0);
    }
  }

  // Epilogue: p[b] = sum_d Yp[b][d]*X[b][d] over wave's 64 d-cols.
  // C/D layout (verified): col = lane&15, row = (lane>>4)*4 + j.
  float p[4][4];
#pragma unroll
  for (int mi = 0; mi < 4; ++mi)
#pragma unroll
    for (int jj = 0; jj < 4; ++jj) p[mi][jj] = 0.f;
#pragma unroll
  for (int mi = 0; mi < 4; ++mi) {
#pragma unroll
    for (int jj = 0; jj < 4; ++jj) {
      const int brow = b0 + mi * 16 + lk * 4 + jj;
      const float* xr = X + (size_t)brow * D_N + wid * 64 + lr;
#pragma unroll
      for (int ni = 0; ni < 4; ++ni)
        p[mi][jj] = fmaf(acc[mi][ni][jj], xr[ni * 16], p[mi][jj]);
    }
  }
#pragma unroll
  for (int mi = 0; mi < 4; ++mi)
#pragma unroll
    for (int jj = 0; jj < 4; ++jj) {
      float v = p[mi][jj];
      v += __shfl_xor(v, 1);
      v += __shfl_xor(v, 2);
      v += __shfl_xor(v, 4);
      v += __shfl_xor(v, 8);
      p[mi][jj] = v;
    }
  __syncthreads();  // all LDS (Ah) reads done before red alias-write
  if (lr == 0) {
#pragma unroll
    for (int mi = 0; mi < 4; ++mi)
#pragma unroll
      for (int jj = 0; jj < 4; ++jj)
        red[wid][mi * 16 + lk * 4 + jj] = p[mi][jj];
  }
  __syncthreads();
  if (tid < 64) {
    const float s = red[0][tid] + red[1][tid] + red[2][tid] + red[3][tid];
    xsx[(size_t)(b0 + tid) * K_N + kk] = s;
  }
}

// Fallback (small ws): in-block convert, 128-tile (round-1 verified path).
__global__ __launch_bounds__(512, 2) void xsx_fallback(
    const float* __restrict__ X, const float* __restrict__ Sigma,
    float* __restrict__ xsx) {
  constexpr int BM = 128, KT = 32;
  __shared__ __align__(16) ushort Ah[BM][KT];
  __shared__ __align__(16) ushort Al[BM][KT];
  __shared__ __align__(16) ushort Bh[D_N][KT];
  __shared__ __align__(16) ushort Bl[D_N][KT];
  __shared__ float red[4][BM];

  const int tid = threadIdx.x;
  const int lane = tid & 63;
  const int wid = tid >> 6;
  const int wm = wid >> 2;
  const int wn = wid & 3;
  const int lr = lane & 15;
  const int lk = lane >> 4;

  const int b0 = blockIdx.x * BM;
  const int kk = blockIdx.y;
  const size_t soff = (size_t)kk * D_N * D_N;

  f32x4 acc[4][4];
#pragma unroll
  for (int mi = 0; mi < 4; ++mi)
#pragma unroll
    for (int ni = 0; ni < 4; ++ni) acc[mi][ni] = (f32x4){0.f, 0.f, 0.f, 0.f};

  for (int ec = 0; ec < D_N / KT; ++ec) {
    const int e0 = ec * KT;
    __syncthreads();
#pragma unroll
    for (int r = 0; r < 2; ++r) {
      const int i = tid + 512 * r;
      const int row = i >> 3, c4 = (i & 7) * 4;
      const float4 v = *(const float4*)(X + (size_t)(b0 + row) * D_N + e0 + c4);
      ushort4 h, l;
      h.x = bf16_rne(v.x); l.x = bf16_rne(v.x - bf16_f32(h.x));
      h.y = bf16_rne(v.y); l.y = bf16_rne(v.y - bf16_f32(h.y));
      h.z = bf16_rne(v.z); l.z = bf16_rne(v.z - bf16_f32(h.z));
      h.w = bf16_rne(v.w); l.w = bf16_rne(v.w - bf16_f32(h.w));
      *(ushort4*)&Ah[row][c4] = h;
      *(ushort4*)&Al[row][c4] = l;
    }
#pragma unroll
    for (int r = 0; r < 4; ++r) {
      const int i = tid + 512 * r;
      const int d = i >> 3, c4 = (i & 7) * 4;
      const float4 v = *(const float4*)(Sigma + soff + (size_t)d * D_N + e0 + c4);
      ushort4 h, l;
      h.x = bf16_rne(v.x); l.x = bf16_rne(v.x - bf16_f32(h.x));
      h.y = bf16_rne(v.y); l.y = bf16_rne(v.y - bf16_f32(h.y));
      h.z = bf16_rne(v.z); l.z = bf16_rne(v.z - bf16_f32(h.z));
      h.w = bf16_rne(v.w); l.w = bf16_rne(v.w - bf16_f32(h.w));
      *(ushort4*)&Bh[d][c4] = h;
      *(ushort4*)&Bl[d][c4] = l;
    }
    __syncthreads();

    bf16x8 ah[4], al[4];
#pragma unroll
    for (int mi = 0; mi < 4; ++mi) {
      ah[mi] = *(const bf16x8*)&Ah[wm * 64 + mi * 16 + lr][lk * 8];
      al[mi] = *(const bf16x8*)&Al[wm * 64 + mi * 16 + lr][lk * 8];
    }
#pragma unroll
    for (int ni = 0; ni < 4; ++ni) {
      const bf16x8 bh = *(const bf16x8*)&Bh[wn * 64 + ni * 16 + lr][lk * 8];
      const bf16x8 bl = *(const bf16x8*)&Bl[wn * 64 + ni * 16 + lr][lk * 8];
#pragma unroll
      for (int mi = 0; mi < 4; ++mi) {
        acc[mi][ni] = __builtin_amdgcn_mfma_f32_16x16x32_bf16(ah[mi], bh, acc[mi][ni], 0, 0, 0);
        acc[mi][ni] = __builtin_amdgcn_mfma_f32_16x16x32_bf16(al[mi], bh, acc[mi][ni], 0, 0, 0);
        acc[mi][ni] = __builtin_amdgcn_mfma_f32_16x16x32_bf16(ah[mi], bl, acc[mi][ni], 0, 0, 0);
      }
    }
  }

  float p[4][4];
#pragma unroll
  for (int mi = 0; mi < 4; ++mi)
#pragma unroll
    for (int jj = 0; jj < 4; ++jj) p[mi][jj] = 0.f;
#pragma unroll
  for (int mi = 0; mi < 4; ++mi) {
#pragma unroll
    for (int jj = 0; jj < 4; ++jj) {
      const int brow = b0 + wm * 64 + mi * 16 + lk * 4 + jj;
      const float* xr = X + (size_t)brow * D_N + wn * 64 + lr;
#pragma unroll
      for (int ni = 0; ni < 4; ++ni)
        p[mi][jj] = fmaf(acc[mi][ni][jj], xr[ni * 16], p[mi][jj]);
    }
  }
#pragma unroll
  for (int mi = 0; mi < 4; ++mi)
#pragma unroll
    for (int jj = 0; jj < 4; ++jj) {
      float v = p[mi][jj];
      v += __shfl_xor(v, 1);
      v += __shfl_xor(v, 2);
      v += __shfl_xor(v, 4);
      v += __shfl_xor(v, 8);
      p[mi][jj] = v;
    }
  if (lr == 0) {
#pragma unroll
    for (int mi = 0; mi < 4; ++mi)
#pragma unroll
      for (int jj = 0; jj < 4; ++jj)
        red[wn][wm * 64 + mi * 16 + lk * 4 + jj] = p[mi][jj];
  }
  __syncthreads();
  if (tid < BM) {
    const float s = red[0][tid] + red[1][tid] + red[2][tid] + red[3][tid];
    xsx[(size_t)(b0 + tid) * K_N + kk] = s;
  }
}

// One wave per batch row b; lane k owns class k in [0,64).
__global__ __launch_bounds__(256) void loss_kernel(
    const float* __restrict__ X, const int* __restrict__ y,
    const float* __restrict__ mu, const int* __restrict__ loss_type,
    const float* __restrict__ xsx, float* __restrict__ out) {
  __shared__ float mu_s[D_N * K_N];  // 64 KB
  __shared__ float x_s[4][D_N];      //  4 KB
  const int tid = threadIdx.x;
  const int wid = tid >> 6;
  const int lane = tid & 63;
  const int b = blockIdx.x * 4 + wid;

  for (int i = tid; i < D_N * K_N / 4; i += 256)
    ((float4*)mu_s)[i] = ((const float4*)mu)[i];
  ((float4*)&x_s[wid][0])[lane] = ((const float4*)(X + (size_t)b * D_N))[lane];
  __syncthreads();

  const int yb = y[b];
  const int lt = loss_type[0];

  float logit = 0.f;
#pragma unroll 8
  for (int d = 0; d < D_N; ++d)
    logit = fmaf(x_s[wid][d], mu_s[d * K_N + lane], logit);

  float term;
  if (lt == 1) {
    const float xv = xsx[(size_t)b * K_N + lane];
    const float psi = sqrtf(fmaxf(xv + logit * logit, 0.f));
    const float bk = (lane <= yb) ? 1.f : 0.f;
    const float kap = ((lane == yb) ? 1.f : 0.f) - 0.5f * bk;
    // psi/2 - softplus(psi) = -psi/2 - log1p(exp(-psi)) for psi >= 0
    term = logit * kap + bk * (-0.5f * psi - log1pf(expf(-psi)));
  } else {
    const float sp = (logit > 0.f) ? (logit + log1pf(expf(-logit)))
                                   : log1pf(expf(logit));
    term = ((lane == yb) ? logit : 0.f) - ((lane <= yb) ? sp : 0.f);
  }
#pragma unroll
  for (int s = 1; s < 64; s <<= 1) term += __shfl_xor(term, s);
  if (lane == 0) out[b] = -term;
}

extern "C" void kernel_launch(void* const* d_in, const int* in_sizes, int n_in,
                              void* d_out, int out_size, void* d_ws, size_t ws_size,
                              hipStream_t stream) {
  const float* X = (const float*)d_in[0];
  const int* y = (const int*)d_in[1];
  const float* mu = (const float*)d_in[2];
  const float* Sigma = (const float*)d_in[3];
  const int* lt = (const int*)d_in[4];
  float* out = (float*)d_out;

  const size_t XN = (size_t)B_N * D_N;        // 2,097,152 elems
  const size_t SN = (size_t)K_N * D_N * D_N;  // 4,194,304 elems
  const size_t xh_off = 0;
  const size_t xl_off = xh_off + XN * 2;
  const size_t sh_off = xl_off + XN * 2;
  const size_t sl_off = sh_off + SN * 2;
  const size_t xsx_off = sl_off + SN * 2;
  const size_t need = xsx_off + (size_t)B_N * K_N * 4;  // ~27.3 MB

  char* w = (char*)d_ws;
  if (ws_size >= need) {
    ushort* Xh = (ushort*)(w + xh_off);
    ushort* Xl = (ushort*)(w + xl_off);
    ushort* Sh = (ushort*)(w + sh_off);
    ushort* Sl = (ushort*)(w + sl_off);
    float* xsx = (float*)(w + xsx_off);
    hipLaunchKernelGGL(convert_kernel, dim3(1024), dim3(256), 0, stream,
                       X, Xh, Xl, (int)(XN / 4));
    hipLaunchKernelGGL(convert_kernel, dim3(2048), dim3(256), 0, stream,
                       Sigma, Sh, Sl, (int)(SN / 4));
    hipLaunchKernelGGL(xsx64_kernel, dim3(8192), dim3(256), 0, stream,
                       X, Xh, Xl, Sh, Sl, xsx);
    hipLaunchKernelGGL(loss_kernel, dim3(B_N / 4), dim3(256), 0, stream,
                       X, y, mu, lt, xsx, out);
  } else {
    float* xsx = (float*)w;  // needs 2 MB
    hipLaunchKernelGGL(xsx_fallback, dim3(B_N / 128, K_N), dim3(512), 0, stream,
                       X, Sigma, xsx);
    hipLaunchKernelGGL(loss_kernel, dim3(B_N / 4), dim3(256), 0, stream,
                       X, y, mu, lt, xsx, out);
  }
}